// Round 8
// baseline (190.100 us; speedup 1.0000x reference)
//
#include <hip/hip_runtime.h>
#include <math.h>

#define HH 96
#define WW 96
#define NB 4
#define NC 64
#define HW (HH*WW)

typedef unsigned short u16;
typedef unsigned int   u32;
typedef __attribute__((ext_vector_type(8))) short bf16x8;
typedef __attribute__((ext_vector_type(4))) float f32x4;

__device__ inline float bf2f(u16 v) { u32 u = ((u32)v) << 16; return __uint_as_float(u); }
__device__ inline u16 f2bf(float f) {
    u32 u = __float_as_uint(f);
    return (u16)((u + 0x7FFFu + ((u >> 16) & 1u)) >> 16);   // RNE
}
__device__ __forceinline__ float elemf(const u32* a, int i) {  // u16 elem i as bf16->f32
    u32 v = a[i >> 1];
    v = (i & 1) ? (v & 0xFFFF0000u) : (v << 16);
    return __uint_as_float(v);
}

// ---------------------------------------------------------------------------
// k_prep: NCHW->NHWC bf16 for x & offset (blocks 0..287) + weight repack into
// MFMA B-fragment order (blocks 288..1151). w_off padded to 16 cots (N=256).
// B-frag: dst[((t*NT+cot)*64+L)*8+j] = B[k][co], k=t*32+(L>>4)*8+j, co=cot*16+(L&15)
// ---------------------------------------------------------------------------
__global__ __launch_bounds__(256) void k_prep(
    const float* __restrict__ x, const float* __restrict__ offset,
    const float* __restrict__ w_off, const float* __restrict__ w_dcn,
    const float* __restrict__ w_c1,
    u16* __restrict__ xt, u16* __restrict__ ot,
    u16* __restrict__ d_off, u16* __restrict__ d_dcn, u16* __restrict__ d_c1) {
    int bx = blockIdx.x;
    int tid = threadIdx.x;
    if (bx < 288) {
        const float* src = (bx < 144) ? x : offset;
        u16* dst = (bx < 144) ? xt : ot;
        int pix = (bx % 144) * 256 + tid;
        int b = pix / HW, hw = pix % HW;
        const float* s = src + b * 64 * HW + hw;
        uint4* dp = (uint4*)(dst + pix * 64);
#pragma unroll
        for (int q = 0; q < 8; ++q) {
            u32 a0 = (u32)f2bf(s[(q*8+0)*HW]) | ((u32)f2bf(s[(q*8+1)*HW]) << 16);
            u32 a1 = (u32)f2bf(s[(q*8+2)*HW]) | ((u32)f2bf(s[(q*8+3)*HW]) << 16);
            u32 a2 = (u32)f2bf(s[(q*8+4)*HW]) | ((u32)f2bf(s[(q*8+5)*HW]) << 16);
            u32 a3 = (u32)f2bf(s[(q*8+6)*HW]) | ((u32)f2bf(s[(q*8+7)*HW]) << 16);
            dp[q] = make_uint4(a0, a1, a2, a3);
        }
        return;
    }
    int rel = bx - 288;
    int m, i0;
    if (rel < 576)      { m = 0; i0 = rel * 256; }
    else if (rel < 720) { m = 1; i0 = (rel - 576) * 256; }
    else                { m = 2; i0 = (rel - 720) * 256; }
    const float* w = (m == 0) ? w_off : ((m == 1) ? w_dcn : w_c1);
    u16* dst = (m == 0) ? d_off : ((m == 1) ? d_dcn : d_c1);
    int NT   = (m == 0) ? 16 : 4;
    int NCO  = (m == 0) ? 216 : 64;
    int i = i0 + tid;
    if (i >= 18 * NT * 512) return;
    int j = i & 7, L = (i >> 3) & 63;
    int cot = (i >> 9) % NT, t = (i >> 9) / NT;
    int k = t * 32 + ((L >> 4) << 3) + j;
    int co = cot * 16 + (L & 15);
    float v = 0.f;
    if (co < NCO) {
        int ci, q;
        if (m == 1) { int c = k & 7, gk = k >> 3; int kk = gk % 9, g = gk / 9; ci = g*8+c; q = kk; }
        else        { q = k >> 6; ci = k & 63; }
        v = w[co * 576 + ci * 9 + q];
    }
    dst[i] = f2bf(v);
}

// ---------------------------------------------------------------------------
// GEMM off v3: barrier-free, LDS-free. Block = 64 pixels x 16 cots.
// 4 waves share the A M-quad (L1-hot); wave owns 2 cots (B L2-hot).
// Per K-step per wave: 2 B loads + 4 A loads + 8 MFMA, fully independent.
// ---------------------------------------------------------------------------
__global__ __launch_bounds__(256) void k_gemm_off(
    const u16* __restrict__ ot, const u16* __restrict__ wtb,
    const float* __restrict__ bias, u16* __restrict__ omr) {
    int tid = threadIdx.x;
    int wid = tid >> 6, L = tid & 63, lr = L & 15, lk = L >> 4;
    int bx = blockIdx.x;
    int mq = bx >> 1, nh = bx & 1;
    int pixblk = mq * 64;
    int b = pixblk / HW;
    int cbase = nh * 8 + wid * 2;
    int yv[4], xv[4];
#pragma unroll
    for (int ms = 0; ms < 4; ++ms) {
        int hw = (pixblk + ms * 16 + lr) % HW;   // 16-pixel groups never straddle rows
        yv[ms] = hw / WW; xv[ms] = hw % WW;
    }

    f32x4 acc[4][2];
#pragma unroll
    for (int ms = 0; ms < 4; ++ms) {
        acc[ms][0] = (f32x4){0.f, 0.f, 0.f, 0.f};
        acc[ms][1] = (f32x4){0.f, 0.f, 0.f, 0.f};
    }

#pragma unroll 6
    for (int t = 0; t < 18; ++t) {
        int q = t >> 1;
        int c0 = (t & 1) * 32 + lk * 8;
        int dy = q / 3 - 1, dx = q % 3 - 1;
        bf16x8 b0 = *(const bf16x8*)(wtb + ((t * 16 + cbase + 0) * 64 + L) * 8);
        bf16x8 b1 = *(const bf16x8*)(wtb + ((t * 16 + cbase + 1) * 64 + L) * 8);
#pragma unroll
        for (int ms = 0; ms < 4; ++ms) {
            int yy = yv[ms] + dy, xx = xv[ms] + dx;
            bf16x8 a = {0,0,0,0,0,0,0,0};
            if (yy >= 0 && yy < HH && xx >= 0 && xx < WW)
                a = *(const bf16x8*)(ot + ((b * HH + yy) * WW + xx) * 64 + c0);
            acc[ms][0] = __builtin_amdgcn_mfma_f32_16x16x32_bf16(a, b0, acc[ms][0], 0, 0, 0);
            acc[ms][1] = __builtin_amdgcn_mfma_f32_16x16x32_bf16(a, b1, acc[ms][1], 0, 0, 0);
        }
    }

#pragma unroll
    for (int ms = 0; ms < 4; ++ms) {
        int pixC = pixblk + ms * 16 + lk * 4;
#pragma unroll
        for (int ct = 0; ct < 2; ++ct) {
            int co = (cbase + ct) * 16 + lr;
            if (co < 216) {
                int cls = co / 72;          // 0:oy 1:ox 2:mask
                int c   = co % 72;
                int g   = c / 9, kk = c % 9;
                int slot = g * 32 + cls * 9 + kk;
                float bs = bias[co];
#pragma unroll
                for (int r = 0; r < 4; ++r) {
                    float v = acc[ms][ct][r] + bs;
                    if (cls == 2) v = 1.f / (1.f + __expf(-v));
                    omr[(pixC + r) * 256 + slot] = f2bf(v);
                }
            }
        }
    }
}

// ---------------------------------------------------------------------------
// Fused deformable sampling + dcn GEMM. 32-pixel tile, single sample phase:
// lane = (pixel p, group g) covers all 8 groups; LDS rows 1152 B, XOR-swizzled.
// ---------------------------------------------------------------------------
__global__ __launch_bounds__(256) void k_sdcn(
    const u16* __restrict__ xt, const u16* __restrict__ omr,
    const u16* __restrict__ wtb, const float* __restrict__ bias,
    u16* __restrict__ fea) {
    __shared__ u16 sv[32 * 576];     // 36864 B
    int tid = threadIdx.x;
    int pixblk = blockIdx.x * 32;
    int p = tid >> 3, g = tid & 7;
    int pix = pixblk + p;
    int b = pixblk / HW;
    int hw = pix % HW, h = hw / WW, w = hw % WW;

    // ---- sample: all 9 taps for (pixel p, group g) ----
    {
        const u16* xb = xt + b * HW * 64 + g * 8;
        const uint4* op = (const uint4*)(omr + (size_t)pix * 256 + g * 32);
        uint4 o0 = op[0], o1 = op[1], o2 = op[2], o3 = op[3];
        u32 oa[16] = {o0.x,o0.y,o0.z,o0.w, o1.x,o1.y,o1.z,o1.w,
                      o2.x,o2.y,o2.z,o2.w, o3.x,o3.y,o3.z,o3.w};
#pragma unroll
        for (int kk = 0; kk < 9; ++kk) {
            float oy   = elemf(oa, kk);
            float ox   = elemf(oa, 9 + kk);
            float mask = elemf(oa, 18 + kk);

            float py = (float)(h + kk / 3 - 1) + oy;
            float px = (float)(w + kk % 3 - 1) + ox;
            float y0f = floorf(py), x0f = floorf(px);
            float fy = py - y0f, fx = px - x0f;
            int y0 = (int)y0f, x0 = (int)x0f, y1 = y0 + 1, x1 = x0 + 1;
            int yc0 = min(max(y0, 0), HH-1), yc1 = min(max(y1, 0), HH-1);
            int xc0 = min(max(x0, 0), WW-1), xc1 = min(max(x1, 0), WW-1);
            float u0 = 1.f - fy, u1 = fy, s0 = 1.f - fx, s1 = fx;
            float w00 = (y0 >= 0 && y0 < HH && x0 >= 0 && x0 < WW) ? u0*s0*mask : 0.f;
            float w01 = (y0 >= 0 && y0 < HH && x1 >= 0 && x1 < WW) ? u0*s1*mask : 0.f;
            float w10 = (y1 >= 0 && y1 < HH && x0 >= 0 && x0 < WW) ? u1*s0*mask : 0.f;
            float w11 = (y1 >= 0 && y1 < HH && x1 >= 0 && x1 < WW) ? u1*s1*mask : 0.f;

            uint4 q00 = *(const uint4*)(xb + (yc0*WW + xc0)*64);
            uint4 q01 = *(const uint4*)(xb + (yc0*WW + xc1)*64);
            uint4 q10 = *(const uint4*)(xb + (yc1*WW + xc0)*64);
            uint4 q11 = *(const uint4*)(xb + (yc1*WW + xc1)*64);

            float r[8];
            {
                float a, bb, c, d;
                a=__uint_as_float(q00.x<<16); bb=__uint_as_float(q01.x<<16); c=__uint_as_float(q10.x<<16); d=__uint_as_float(q11.x<<16);
                r[0]=w00*a+w01*bb+w10*c+w11*d;
                a=__uint_as_float(q00.x&0xFFFF0000u); bb=__uint_as_float(q01.x&0xFFFF0000u); c=__uint_as_float(q10.x&0xFFFF0000u); d=__uint_as_float(q11.x&0xFFFF0000u);
                r[1]=w00*a+w01*bb+w10*c+w11*d;
                a=__uint_as_float(q00.y<<16); bb=__uint_as_float(q01.y<<16); c=__uint_as_float(q10.y<<16); d=__uint_as_float(q11.y<<16);
                r[2]=w00*a+w01*bb+w10*c+w11*d;
                a=__uint_as_float(q00.y&0xFFFF0000u); bb=__uint_as_float(q01.y&0xFFFF0000u); c=__uint_as_float(q10.y&0xFFFF0000u); d=__uint_as_float(q11.y&0xFFFF0000u);
                r[3]=w00*a+w01*bb+w10*c+w11*d;
                a=__uint_as_float(q00.z<<16); bb=__uint_as_float(q01.z<<16); c=__uint_as_float(q10.z<<16); d=__uint_as_float(q11.z<<16);
                r[4]=w00*a+w01*bb+w10*c+w11*d;
                a=__uint_as_float(q00.z&0xFFFF0000u); bb=__uint_as_float(q01.z&0xFFFF0000u); c=__uint_as_float(q10.z&0xFFFF0000u); d=__uint_as_float(q11.z&0xFFFF0000u);
                r[5]=w00*a+w01*bb+w10*c+w11*d;
                a=__uint_as_float(q00.w<<16); bb=__uint_as_float(q01.w<<16); c=__uint_as_float(q10.w<<16); d=__uint_as_float(q11.w<<16);
                r[6]=w00*a+w01*bb+w10*c+w11*d;
                a=__uint_as_float(q00.w&0xFFFF0000u); bb=__uint_as_float(q01.w&0xFFFF0000u); c=__uint_as_float(q10.w&0xFFFF0000u); d=__uint_as_float(q11.w&0xFFFF0000u);
                r[7]=w00*a+w01*bb+w10*c+w11*d;
            }
            u32 a0 = (u32)f2bf(r[0]) | ((u32)f2bf(r[1]) << 16);
            u32 a1 = (u32)f2bf(r[2]) | ((u32)f2bf(r[3]) << 16);
            u32 a2 = (u32)f2bf(r[4]) | ((u32)f2bf(r[5]) << 16);
            u32 a3 = (u32)f2bf(r[6]) | ((u32)f2bf(r[7]) << 16);
            int slot = g * 9 + kk;
            *(uint4*)((char*)sv + p * 1152 + ((slot * 16) ^ ((p & 7) << 4))) = make_uint4(a0, a1, a2, a3);
        }
    }
    __syncthreads();

    // ---- MFMA: M=32 x K=576 x N=64; wave (wid): pixels (wid&1)*16.., cots (wid>>1)*2.. ----
    int wid = tid >> 6, L = tid & 63, lr = L & 15, lk = L >> 4;
    int pbase = (wid & 1) * 16, cbase = (wid >> 1) * 2;
    int arow = pbase + lr;

    f32x4 acc[2];
    acc[0] = (f32x4){0.f, 0.f, 0.f, 0.f};
    acc[1] = (f32x4){0.f, 0.f, 0.f, 0.f};
#pragma unroll
    for (int t = 0; t < 18; ++t) {
        bf16x8 a = *(const bf16x8*)((const char*)sv + arow * 1152 + (((t * 4 + lk) * 16) ^ ((arow & 7) << 4)));
#pragma unroll
        for (int ct = 0; ct < 2; ++ct) {
            bf16x8 bf = *(const bf16x8*)(wtb + ((t * 4 + cbase + ct) * 64 + L) * 8);
            acc[ct] = __builtin_amdgcn_mfma_f32_16x16x32_bf16(a, bf, acc[ct], 0, 0, 0);
        }
    }
#pragma unroll
    for (int ct = 0; ct < 2; ++ct) {
        int co = (cbase + ct) * 16 + lr;
        float bs = bias[co];
#pragma unroll
        for (int r = 0; r < 4; ++r) {
            float v = acc[ct][r] + bs;
            v = (v >= 0.f) ? v : 0.2f * v;
            fea[(pixblk + pbase + lk * 4 + r) * 64 + co] = f2bf(v);
        }
    }
}

// ---------------------------------------------------------------------------
// GEMM conv1: out (f32 NCHW) = im2col(fea) x w_conv1 + bias + x
// ---------------------------------------------------------------------------
__global__ __launch_bounds__(256) void k_gemm_c1(
    const u16* __restrict__ fea, const u16* __restrict__ wtb,
    const float* __restrict__ bias, const float* __restrict__ xres,
    float* __restrict__ out) {
    __shared__ __align__(16) char smraw[36864];
    u16* lb = (u16*)smraw;
    int tid = threadIdx.x;
    int wid = tid >> 6, L = tid & 63, lr = L & 15, lk = L >> 4;
    int pixblk = blockIdx.x * 64;
    int pixbase = pixblk + wid * 16;
    int pixA = pixbase + lr;
    int b = pixblk / HW;
    int hw = pixA % HW, y = hw / WW, x = hw % WW;

    f32x4 acc[4];
#pragma unroll
    for (int i = 0; i < 4; ++i) acc[i] = (f32x4){0.f, 0.f, 0.f, 0.f};

    {
        const uint4* s = (const uint4*)wtb;
        uint4* d = (uint4*)lb;
#pragma unroll
        for (int i = 0; i < 9; ++i) d[tid + i * 256] = s[tid + i * 256];
    }
    __syncthreads();
    for (int half = 0; half < 2; ++half) {
        int tbase = half * 9;
#pragma unroll
        for (int tl = 0; tl < 9; ++tl) {
            int t = tbase + tl;
            int q = t >> 1;
            int c0 = (t & 1) * 32 + lk * 8;
            int dy = q / 3 - 1, dx = q % 3 - 1;
            int yy = y + dy, xx = x + dx;
            bf16x8 a = {0,0,0,0,0,0,0,0};
            if (yy >= 0 && yy < HH && xx >= 0 && xx < WW)
                a = *(const bf16x8*)(fea + ((b * HH + yy) * WW + xx) * 64 + c0);
            const u16* wp = lb + (tl * 256 + L) * 8;
#pragma unroll
            for (int cot = 0; cot < 4; ++cot) {
                bf16x8 bf = *(const bf16x8*)(wp + cot * 512);
                acc[cot] = __builtin_amdgcn_mfma_f32_16x16x32_bf16(a, bf, acc[cot], 0, 0, 0);
            }
        }
        __syncthreads();
        if (half == 0) {
            const uint4* s = (const uint4*)(wtb + 18432);
            uint4* d = (uint4*)lb;
#pragma unroll
            for (int i = 0; i < 9; ++i) d[tid + i * 256] = s[tid + i * 256];
            __syncthreads();
        }
    }
    float* ob = (float*)smraw;
#pragma unroll
    for (int cot = 0; cot < 4; ++cot) {
#pragma unroll
        for (int r = 0; r < 4; ++r)
            ob[(wid * 16 + lk * 4 + r) * 66 + cot * 16 + lr] = acc[cot][r];
    }
    __syncthreads();
    int p = tid & 63, cg = tid >> 6;
    int hw0 = pixblk % HW;
#pragma unroll
    for (int i = 0; i < 16; ++i) {
        int co = cg * 16 + i;
        int idx = (b * 64 + co) * HW + hw0 + p;
        out[idx] = ob[p * 66 + co] + bias[co] + xres[idx];
    }
}

// ---------------------------------------------------------------------------
extern "C" void kernel_launch(void* const* d_in, const int* in_sizes, int n_in,
                              void* d_out, int out_size, void* d_ws, size_t ws_size,
                              hipStream_t stream) {
    const float* x       = (const float*)d_in[0];
    const float* offset  = (const float*)d_in[1];
    const float* w_off   = (const float*)d_in[2];
    const float* b_off   = (const float*)d_in[3];
    const float* w_dcn   = (const float*)d_in[4];
    const float* b_dcn   = (const float*)d_in[5];
    const float* w_conv1 = (const float*)d_in[6];
    const float* b_conv1 = (const float*)d_in[7];
    float* out = (float*)d_out;

    char* ws = (char*)d_ws;
    u16* omr     = (u16*)(ws);                        // 36864*256*2 = 18,874,368
    u16* xt      = (u16*)(ws + 18874368);             //  4,718,592
    u16* ot      = (u16*)(ws + 23592960);             //  4,718,592
    u16* fea     = (u16*)(ws + 28311552);             //  4,718,592
    u16* wtb_off = (u16*)(ws + 33030144);             // 18*16*512*2 = 294,912
    u16* wtb_dcn = (u16*)(ws + 33325056);             //     73,728
    u16* wtb_c1  = (u16*)(ws + 33398784);             //     73,728

    hipLaunchKernelGGL(k_prep, dim3(1152), dim3(256), 0, stream,
                       x, offset, w_off, w_dcn, w_conv1, xt, ot, wtb_off, wtb_dcn, wtb_c1);
    hipLaunchKernelGGL(k_gemm_off, dim3(1152), dim3(256), 0, stream, ot, wtb_off, b_off, omr);
    hipLaunchKernelGGL(k_sdcn, dim3(1152), dim3(256), 0, stream, xt, omr, wtb_dcn, b_dcn, fea);
    hipLaunchKernelGGL(k_gemm_c1, dim3(576), dim3(256), 0, stream, fea, wtb_c1, b_conv1, x, out);
}

// Round 10
// 162.006 us; speedup vs baseline: 1.1734x; 1.1734x over previous
//
#include <hip/hip_runtime.h>
#include <math.h>

#define HH 96
#define WW 96
#define NB 4
#define NC 64
#define HW (HH*WW)
#define PH 98
#define PW 98
#define PHW (PH*PW)          // 9604 padded pixels per batch
#define NPP (NB*PHW)         // 38416

typedef unsigned short u16;
typedef unsigned int   u32;
typedef __attribute__((ext_vector_type(8))) short bf16x8;
typedef __attribute__((ext_vector_type(4))) float f32x4;

__device__ inline float bf2f(u16 v) { u32 u = ((u32)v) << 16; return __uint_as_float(u); }
__device__ inline u16 f2bf(float f) {
    u32 u = __float_as_uint(f);
    return (u16)((u + 0x7FFFu + ((u >> 16) & 1u)) >> 16);   // RNE
}
__device__ __forceinline__ float elemf(const u32* a, int i) {  // u16 elem i as bf16->f32
    u32 v = a[i >> 1];
    v = (i & 1) ? (v & 0xFFFF0000u) : (v << 16);
    return __uint_as_float(v);
}

// ---------------------------------------------------------------------------
// k_prep:
//  blocks 0..143    : x NCHW->NHWC bf16 (xt)
//  blocks 144..294  : offset NCHW -> HALO-PADDED NHWC bf16 (otp, 98x98, zero border)
//  blocks 295..1158 : weight repack into MFMA B-frag order (w_off padded to 16 cots)
// B-frag: dst[((t*NT+cot)*64+L)*8+j] = B[k][co], k=t*32+(L>>4)*8+j, co=cot*16+(L&15)
// ---------------------------------------------------------------------------
__global__ __launch_bounds__(256) void k_prep(
    const float* __restrict__ x, const float* __restrict__ offset,
    const float* __restrict__ w_off, const float* __restrict__ w_dcn,
    const float* __restrict__ w_c1,
    u16* __restrict__ xt, u16* __restrict__ otp,
    u16* __restrict__ d_off, u16* __restrict__ d_dcn, u16* __restrict__ d_c1) {
    int bx = blockIdx.x;
    int tid = threadIdx.x;
    if (bx < 144) {
        int pix = bx * 256 + tid;
        int b = pix / HW, hw = pix % HW;
        const float* s = x + b * 64 * HW + hw;
        uint4* dp = (uint4*)(xt + pix * 64);
#pragma unroll
        for (int q = 0; q < 8; ++q) {
            u32 a0 = (u32)f2bf(s[(q*8+0)*HW]) | ((u32)f2bf(s[(q*8+1)*HW]) << 16);
            u32 a1 = (u32)f2bf(s[(q*8+2)*HW]) | ((u32)f2bf(s[(q*8+3)*HW]) << 16);
            u32 a2 = (u32)f2bf(s[(q*8+4)*HW]) | ((u32)f2bf(s[(q*8+5)*HW]) << 16);
            u32 a3 = (u32)f2bf(s[(q*8+6)*HW]) | ((u32)f2bf(s[(q*8+7)*HW]) << 16);
            dp[q] = make_uint4(a0, a1, a2, a3);
        }
        return;
    }
    if (bx < 295) {
        int pp = (bx - 144) * 256 + tid;
        if (pp >= NPP) return;
        int bp = pp / PHW, rem = pp % PHW;
        int py = rem / PW, px = rem % PW;
        int y = py - 1, xx = px - 1;
        uint4* dp = (uint4*)(otp + (size_t)pp * 64);
        if (y >= 0 && y < HH && xx >= 0 && xx < WW) {
            const float* s = offset + bp * 64 * HW + y * WW + xx;
#pragma unroll
            for (int q = 0; q < 8; ++q) {
                u32 a0 = (u32)f2bf(s[(q*8+0)*HW]) | ((u32)f2bf(s[(q*8+1)*HW]) << 16);
                u32 a1 = (u32)f2bf(s[(q*8+2)*HW]) | ((u32)f2bf(s[(q*8+3)*HW]) << 16);
                u32 a2 = (u32)f2bf(s[(q*8+4)*HW]) | ((u32)f2bf(s[(q*8+5)*HW]) << 16);
                u32 a3 = (u32)f2bf(s[(q*8+6)*HW]) | ((u32)f2bf(s[(q*8+7)*HW]) << 16);
                dp[q] = make_uint4(a0, a1, a2, a3);
            }
        } else {
            uint4 z = make_uint4(0u, 0u, 0u, 0u);
#pragma unroll
            for (int q = 0; q < 8; ++q) dp[q] = z;
        }
        return;
    }
    int rel = bx - 295;
    int m, i0;
    if (rel < 576)      { m = 0; i0 = rel * 256; }
    else if (rel < 720) { m = 1; i0 = (rel - 576) * 256; }
    else                { m = 2; i0 = (rel - 720) * 256; }
    const float* w = (m == 0) ? w_off : ((m == 1) ? w_dcn : w_c1);
    u16* dst = (m == 0) ? d_off : ((m == 1) ? d_dcn : d_c1);
    int NT   = (m == 0) ? 16 : 4;
    int NCO  = (m == 0) ? 216 : 64;
    int i = i0 + tid;
    if (i >= 18 * NT * 512) return;
    int j = i & 7, L = (i >> 3) & 63;
    int cot = (i >> 9) % NT, t = (i >> 9) / NT;
    int k = t * 32 + ((L >> 4) << 3) + j;
    int co = cot * 16 + (L & 15);
    float v = 0.f;
    if (co < NCO) {
        int ci, q;
        if (m == 1) { int c = k & 7, gk = k >> 3; int kk = gk % 9, g = gk / 9; ci = g*8+c; q = kk; }
        else        { q = k >> 6; ci = k & 63; }
        v = w[co * 576 + ci * 9 + q];
    }
    dst[i] = f2bf(v);
}

// ---------------------------------------------------------------------------
// GEMM off (R5 structure + halo A + coalesced epilogue):
// block = 64 pixels, 4 waves M-split (16 px each), all 14 cots per wave.
// B tile (14 KB) staged in LDS per K-step. A loads branchless via halo pad.
// Epilogue: acc -> LDS (32 KB) scatter (co<216 guard!), coalesced rows to omr.
// ---------------------------------------------------------------------------
__global__ __launch_bounds__(256) void k_gemm_off(
    const u16* __restrict__ otp, const u16* __restrict__ wtb,
    const float* __restrict__ bias, u16* __restrict__ omr) {
    __shared__ __align__(16) char smem[32768];
    u16* lb = (u16*)smem;
    int tid = threadIdx.x;
    int wid = tid >> 6, L = tid & 63, lr = L & 15, lk = L >> 4;
    int pixblk = blockIdx.x * 64;
    int pixA = pixblk + wid * 16 + lr;
    int b = pixblk / HW;
    int hw = pixA % HW, y = hw / WW, x = hw % WW;
    int Abase = ((b * PH + y + 1) * PW + (x + 1)) * 64;

    f32x4 acc[14];
#pragma unroll
    for (int i = 0; i < 14; ++i) acc[i] = (f32x4){0.f, 0.f, 0.f, 0.f};

    for (int t = 0; t < 18; ++t) {
        if (t) __syncthreads();
        {
            const uint4* s = (const uint4*)(wtb + t * 8192);   // 16-cot stride; stage first 14
            uint4* d = (uint4*)lb;
            for (int i = tid; i < 896; i += 256) d[i] = s[i];
        }
        __syncthreads();
        int q = t >> 1;
        int c0 = (t & 1) * 32 + lk * 8;
        int aoff = ((q / 3 - 1) * PW + (q % 3 - 1)) * 64 + c0;
        bf16x8 a = *(const bf16x8*)(otp + Abase + aoff);       // branchless (halo)
        const u16* wp = lb + L * 8;
#pragma unroll
        for (int cot = 0; cot < 14; ++cot) {
            bf16x8 bf = *(const bf16x8*)(wp + cot * 512);
            acc[cot] = __builtin_amdgcn_mfma_f32_16x16x32_bf16(a, bf, acc[cot], 0, 0, 0);
        }
    }

    // epilogue: scatter to LDS (only real channels), then coalesced copy to omr
    __syncthreads();
    u16* om_s = (u16*)smem;
#pragma unroll
    for (int cot = 0; cot < 14; ++cot) {
        int co = cot * 16 + lr;
        if (co < 216) {
            int cls = co / 72;          // 0:oy 1:ox 2:mask
            int c   = co % 72;
            int g   = c / 9, kk = c % 9;
            int slot = g * 32 + cls * 9 + kk;
            float bs = bias[co];
#pragma unroll
            for (int r = 0; r < 4; ++r) {
                float v = acc[cot][r] + bs;
                if (cls == 2) v = 1.f / (1.f + __expf(-v));
                om_s[(wid * 16 + lk * 4 + r) * 256 + slot] = f2bf(v);
            }
        }
    }
    __syncthreads();
    {
        const uint4* s = (const uint4*)om_s;
        uint4* d = (uint4*)(omr + (size_t)pixblk * 256);
#pragma unroll
        for (int i = 0; i < 8; ++i) d[tid + i * 256] = s[tid + i * 256];
    }
}

// ---------------------------------------------------------------------------
// Fused deformable sampling + dcn GEMM. 32-pixel tile, single sample phase:
// lane = (pixel p, group g) covers all 8 groups; LDS rows 1152 B, XOR-swizzled.
// ---------------------------------------------------------------------------
__global__ __launch_bounds__(256) void k_sdcn(
    const u16* __restrict__ xt, const u16* __restrict__ omr,
    const u16* __restrict__ wtb, const float* __restrict__ bias,
    u16* __restrict__ fea) {
    __shared__ u16 sv[32 * 576];     // 36864 B
    int tid = threadIdx.x;
    int pixblk = blockIdx.x * 32;
    int p = tid >> 3, g = tid & 7;
    int pix = pixblk + p;
    int b = pixblk / HW;
    int hw = pix % HW, h = hw / WW, w = hw % WW;

    // ---- sample: all 9 taps for (pixel p, group g) ----
    {
        const u16* xb = xt + b * HW * 64 + g * 8;
        const uint4* op = (const uint4*)(omr + (size_t)pix * 256 + g * 32);
        uint4 o0 = op[0], o1 = op[1], o2 = op[2], o3 = op[3];
        u32 oa[16] = {o0.x,o0.y,o0.z,o0.w, o1.x,o1.y,o1.z,o1.w,
                      o2.x,o2.y,o2.z,o2.w, o3.x,o3.y,o3.z,o3.w};
#pragma unroll
        for (int kk = 0; kk < 9; ++kk) {
            float oy   = elemf(oa, kk);
            float ox   = elemf(oa, 9 + kk);
            float mask = elemf(oa, 18 + kk);

            float py = (float)(h + kk / 3 - 1) + oy;
            float px = (float)(w + kk % 3 - 1) + ox;
            float y0f = floorf(py), x0f = floorf(px);
            float fy = py - y0f, fx = px - x0f;
            int y0 = (int)y0f, x0 = (int)x0f, y1 = y0 + 1, x1 = x0 + 1;
            int yc0 = min(max(y0, 0), HH-1), yc1 = min(max(y1, 0), HH-1);
            int xc0 = min(max(x0, 0), WW-1), xc1 = min(max(x1, 0), WW-1);
            float u0 = 1.f - fy, u1 = fy, s0 = 1.f - fx, s1 = fx;
            float w00 = (y0 >= 0 && y0 < HH && x0 >= 0 && x0 < WW) ? u0*s0*mask : 0.f;
            float w01 = (y0 >= 0 && y0 < HH && x1 >= 0 && x1 < WW) ? u0*s1*mask : 0.f;
            float w10 = (y1 >= 0 && y1 < HH && x0 >= 0 && x0 < WW) ? u1*s0*mask : 0.f;
            float w11 = (y1 >= 0 && y1 < HH && x1 >= 0 && x1 < WW) ? u1*s1*mask : 0.f;

            uint4 q00 = *(const uint4*)(xb + (yc0*WW + xc0)*64);
            uint4 q01 = *(const uint4*)(xb + (yc0*WW + xc1)*64);
            uint4 q10 = *(const uint4*)(xb + (yc1*WW + xc0)*64);
            uint4 q11 = *(const uint4*)(xb + (yc1*WW + xc1)*64);

            float r[8];
            {
                float a, bb, c, d;
                a=__uint_as_float(q00.x<<16); bb=__uint_as_float(q01.x<<16); c=__uint_as_float(q10.x<<16); d=__uint_as_float(q11.x<<16);
                r[0]=w00*a+w01*bb+w10*c+w11*d;
                a=__uint_as_float(q00.x&0xFFFF0000u); bb=__uint_as_float(q01.x&0xFFFF0000u); c=__uint_as_float(q10.x&0xFFFF0000u); d=__uint_as_float(q11.x&0xFFFF0000u);
                r[1]=w00*a+w01*bb+w10*c+w11*d;
                a=__uint_as_float(q00.y<<16); bb=__uint_as_float(q01.y<<16); c=__uint_as_float(q10.y<<16); d=__uint_as_float(q11.y<<16);
                r[2]=w00*a+w01*bb+w10*c+w11*d;
                a=__uint_as_float(q00.y&0xFFFF0000u); bb=__uint_as_float(q01.y&0xFFFF0000u); c=__uint_as_float(q10.y&0xFFFF0000u); d=__uint_as_float(q11.y&0xFFFF0000u);
                r[3]=w00*a+w01*bb+w10*c+w11*d;
                a=__uint_as_float(q00.z<<16); bb=__uint_as_float(q01.z<<16); c=__uint_as_float(q10.z<<16); d=__uint_as_float(q11.z<<16);
                r[4]=w00*a+w01*bb+w10*c+w11*d;
                a=__uint_as_float(q00.z&0xFFFF0000u); bb=__uint_as_float(q01.z&0xFFFF0000u); c=__uint_as_float(q10.z&0xFFFF0000u); d=__uint_as_float(q11.z&0xFFFF0000u);
                r[5]=w00*a+w01*bb+w10*c+w11*d;
                a=__uint_as_float(q00.w<<16); bb=__uint_as_float(q01.w<<16); c=__uint_as_float(q10.w<<16); d=__uint_as_float(q11.w<<16);
                r[6]=w00*a+w01*bb+w10*c+w11*d;
                a=__uint_as_float(q00.w&0xFFFF0000u); bb=__uint_as_float(q01.w&0xFFFF0000u); c=__uint_as_float(q10.w&0xFFFF0000u); d=__uint_as_float(q11.w&0xFFFF0000u);
                r[7]=w00*a+w01*bb+w10*c+w11*d;
            }
            u32 a0 = (u32)f2bf(r[0]) | ((u32)f2bf(r[1]) << 16);
            u32 a1 = (u32)f2bf(r[2]) | ((u32)f2bf(r[3]) << 16);
            u32 a2 = (u32)f2bf(r[4]) | ((u32)f2bf(r[5]) << 16);
            u32 a3 = (u32)f2bf(r[6]) | ((u32)f2bf(r[7]) << 16);
            int slot = g * 9 + kk;
            *(uint4*)((char*)sv + p * 1152 + ((slot * 16) ^ ((p & 7) << 4))) = make_uint4(a0, a1, a2, a3);
        }
    }
    __syncthreads();

    // ---- MFMA: M=32 x K=576 x N=64; wave (wid): pixels (wid&1)*16.., cots (wid>>1)*2.. ----
    int wid = tid >> 6, L = tid & 63, lr = L & 15, lk = L >> 4;
    int pbase = (wid & 1) * 16, cbase = (wid >> 1) * 2;
    int arow = pbase + lr;

    f32x4 acc[2];
    acc[0] = (f32x4){0.f, 0.f, 0.f, 0.f};
    acc[1] = (f32x4){0.f, 0.f, 0.f, 0.f};
#pragma unroll
    for (int t = 0; t < 18; ++t) {
        bf16x8 a = *(const bf16x8*)((const char*)sv + arow * 1152 + (((t * 4 + lk) * 16) ^ ((arow & 7) << 4)));
#pragma unroll
        for (int ct = 0; ct < 2; ++ct) {
            bf16x8 bf = *(const bf16x8*)(wtb + ((t * 4 + cbase + ct) * 64 + L) * 8);
            acc[ct] = __builtin_amdgcn_mfma_f32_16x16x32_bf16(a, bf, acc[ct], 0, 0, 0);
        }
    }
#pragma unroll
    for (int ct = 0; ct < 2; ++ct) {
        int co = (cbase + ct) * 16 + lr;
        float bs = bias[co];
#pragma unroll
        for (int r = 0; r < 4; ++r) {
            float v = acc[ct][r] + bs;
            v = (v >= 0.f) ? v : 0.2f * v;
            fea[(pixblk + pbase + lk * 4 + r) * 64 + co] = f2bf(v);
        }
    }
}

// ---------------------------------------------------------------------------
// GEMM conv1: out (f32 NCHW) = im2col(fea) x w_conv1 + bias + x
// ---------------------------------------------------------------------------
__global__ __launch_bounds__(256) void k_gemm_c1(
    const u16* __restrict__ fea, const u16* __restrict__ wtb,
    const float* __restrict__ bias, const float* __restrict__ xres,
    float* __restrict__ out) {
    __shared__ __align__(16) char smraw[36864];
    u16* lb = (u16*)smraw;
    int tid = threadIdx.x;
    int wid = tid >> 6, L = tid & 63, lr = L & 15, lk = L >> 4;
    int pixblk = blockIdx.x * 64;
    int pixbase = pixblk + wid * 16;
    int pixA = pixbase + lr;
    int b = pixblk / HW;
    int hw = pixA % HW, y = hw / WW, x = hw % WW;

    f32x4 acc[4];
#pragma unroll
    for (int i = 0; i < 4; ++i) acc[i] = (f32x4){0.f, 0.f, 0.f, 0.f};

    {
        const uint4* s = (const uint4*)wtb;
        uint4* d = (uint4*)lb;
#pragma unroll
        for (int i = 0; i < 9; ++i) d[tid + i * 256] = s[tid + i * 256];
    }
    __syncthreads();
    for (int half = 0; half < 2; ++half) {
        int tbase = half * 9;
#pragma unroll
        for (int tl = 0; tl < 9; ++tl) {
            int t = tbase + tl;
            int q = t >> 1;
            int c0 = (t & 1) * 32 + lk * 8;
            int dy = q / 3 - 1, dx = q % 3 - 1;
            int yy = y + dy, xx = x + dx;
            bf16x8 a = {0,0,0,0,0,0,0,0};
            if (yy >= 0 && yy < HH && xx >= 0 && xx < WW)
                a = *(const bf16x8*)(fea + ((b * HH + yy) * WW + xx) * 64 + c0);
            const u16* wp = lb + (tl * 256 + L) * 8;
#pragma unroll
            for (int cot = 0; cot < 4; ++cot) {
                bf16x8 bf = *(const bf16x8*)(wp + cot * 512);
                acc[cot] = __builtin_amdgcn_mfma_f32_16x16x32_bf16(a, bf, acc[cot], 0, 0, 0);
            }
        }
        __syncthreads();
        if (half == 0) {
            const uint4* s = (const uint4*)(wtb + 18432);
            uint4* d = (uint4*)lb;
#pragma unroll
            for (int i = 0; i < 9; ++i) d[tid + i * 256] = s[tid + i * 256];
            __syncthreads();
        }
    }
    float* ob = (float*)smraw;
#pragma unroll
    for (int cot = 0; cot < 4; ++cot) {
#pragma unroll
        for (int r = 0; r < 4; ++r)
            ob[(wid * 16 + lk * 4 + r) * 66 + cot * 16 + lr] = acc[cot][r];
    }
    __syncthreads();
    int p = tid & 63, cg = tid >> 6;
    int hw0 = pixblk % HW;
#pragma unroll
    for (int i = 0; i < 16; ++i) {
        int co = cg * 16 + i;
        int idx = (b * 64 + co) * HW + hw0 + p;
        out[idx] = ob[p * 66 + co] + bias[co] + xres[idx];
    }
}

// ---------------------------------------------------------------------------
extern "C" void kernel_launch(void* const* d_in, const int* in_sizes, int n_in,
                              void* d_out, int out_size, void* d_ws, size_t ws_size,
                              hipStream_t stream) {
    const float* x       = (const float*)d_in[0];
    const float* offset  = (const float*)d_in[1];
    const float* w_off   = (const float*)d_in[2];
    const float* b_off   = (const float*)d_in[3];
    const float* w_dcn   = (const float*)d_in[4];
    const float* b_dcn   = (const float*)d_in[5];
    const float* w_conv1 = (const float*)d_in[6];
    const float* b_conv1 = (const float*)d_in[7];
    float* out = (float*)d_out;

    char* ws = (char*)d_ws;
    u16* omr     = (u16*)(ws);                        // 36864*256*2 = 18,874,368
    u16* xt      = (u16*)(ws + 18874368);             //  4,718,592
    u16* otp     = (u16*)(ws + 23592960);             // 38416*64*2 = 4,917,248 (halo)
    u16* fea     = (u16*)(ws + 28510208);             //  4,718,592
    u16* wtb_off = (u16*)(ws + 33228800);             // 18*16*512*2 = 294,912
    u16* wtb_dcn = (u16*)(ws + 33523712);             //     73,728
    u16* wtb_c1  = (u16*)(ws + 33597440);             //     73,728

    hipLaunchKernelGGL(k_prep, dim3(1159), dim3(256), 0, stream,
                       x, offset, w_off, w_dcn, w_conv1, xt, otp, wtb_off, wtb_dcn, wtb_c1);
    hipLaunchKernelGGL(k_gemm_off, dim3(576), dim3(256), 0, stream, otp, wtb_off, b_off, omr);
    hipLaunchKernelGGL(k_sdcn, dim3(1152), dim3(256), 0, stream, xt, omr, wtb_dcn, b_dcn, fea);
    hipLaunchKernelGGL(k_gemm_c1, dim3(576), dim3(256), 0, stream, fea, wtb_c1, b_conv1, x, out);
}

// Round 11
// 160.992 us; speedup vs baseline: 1.1808x; 1.0063x over previous
//
#include <hip/hip_runtime.h>
#include <math.h>

#define HH 96
#define WW 96
#define NB 4
#define NC 64
#define HW (HH*WW)
#define PH 98
#define PW 98
#define PHW (PH*PW)          // 9604 padded pixels per batch
#define NPP (NB*PHW)         // 38416

typedef unsigned short u16;
typedef unsigned int   u32;
typedef __attribute__((ext_vector_type(8))) short bf16x8;
typedef __attribute__((ext_vector_type(4))) float f32x4;

__device__ inline float bf2f(u16 v) { u32 u = ((u32)v) << 16; return __uint_as_float(u); }
__device__ inline u16 f2bf(float f) {
    u32 u = __float_as_uint(f);
    return (u16)((u + 0x7FFFu + ((u >> 16) & 1u)) >> 16);   // RNE
}
__device__ __forceinline__ float elemf(const u32* a, int i) {  // u16 elem i as bf16->f32
    u32 v = a[i >> 1];
    v = (i & 1) ? (v & 0xFFFF0000u) : (v << 16);
    return __uint_as_float(v);
}

// ---------------------------------------------------------------------------
// k_prep:
//  blocks 0..143    : x NCHW->NHWC bf16 (xt)
//  blocks 144..294  : offset NCHW -> halo-padded NHWC bf16 (otp, 98x98, zero border)
//  blocks 295..445  : zero feap (halo fea buffer)
//  blocks 446..1309 : weight repack into MFMA B-frag order (w_off padded to 16 cots)
// B-frag: dst[((t*NT+cot)*64+L)*8+j] = B[k][co], k=t*32+(L>>4)*8+j, co=cot*16+(L&15)
// ---------------------------------------------------------------------------
__global__ __launch_bounds__(256) void k_prep(
    const float* __restrict__ x, const float* __restrict__ offset,
    const float* __restrict__ w_off, const float* __restrict__ w_dcn,
    const float* __restrict__ w_c1,
    u16* __restrict__ xt, u16* __restrict__ otp, u16* __restrict__ feap,
    u16* __restrict__ d_off, u16* __restrict__ d_dcn, u16* __restrict__ d_c1) {
    int bx = blockIdx.x;
    int tid = threadIdx.x;
    if (bx < 144) {
        int pix = bx * 256 + tid;
        int b = pix / HW, hw = pix % HW;
        const float* s = x + b * 64 * HW + hw;
        uint4* dp = (uint4*)(xt + pix * 64);
#pragma unroll
        for (int q = 0; q < 8; ++q) {
            u32 a0 = (u32)f2bf(s[(q*8+0)*HW]) | ((u32)f2bf(s[(q*8+1)*HW]) << 16);
            u32 a1 = (u32)f2bf(s[(q*8+2)*HW]) | ((u32)f2bf(s[(q*8+3)*HW]) << 16);
            u32 a2 = (u32)f2bf(s[(q*8+4)*HW]) | ((u32)f2bf(s[(q*8+5)*HW]) << 16);
            u32 a3 = (u32)f2bf(s[(q*8+6)*HW]) | ((u32)f2bf(s[(q*8+7)*HW]) << 16);
            dp[q] = make_uint4(a0, a1, a2, a3);
        }
        return;
    }
    if (bx < 295) {
        int pp = (bx - 144) * 256 + tid;
        if (pp >= NPP) return;
        int bp = pp / PHW, rem = pp % PHW;
        int py = rem / PW, px = rem % PW;
        int y = py - 1, xx = px - 1;
        uint4* dp = (uint4*)(otp + (size_t)pp * 64);
        if (y >= 0 && y < HH && xx >= 0 && xx < WW) {
            const float* s = offset + bp * 64 * HW + y * WW + xx;
#pragma unroll
            for (int q = 0; q < 8; ++q) {
                u32 a0 = (u32)f2bf(s[(q*8+0)*HW]) | ((u32)f2bf(s[(q*8+1)*HW]) << 16);
                u32 a1 = (u32)f2bf(s[(q*8+2)*HW]) | ((u32)f2bf(s[(q*8+3)*HW]) << 16);
                u32 a2 = (u32)f2bf(s[(q*8+4)*HW]) | ((u32)f2bf(s[(q*8+5)*HW]) << 16);
                u32 a3 = (u32)f2bf(s[(q*8+6)*HW]) | ((u32)f2bf(s[(q*8+7)*HW]) << 16);
                dp[q] = make_uint4(a0, a1, a2, a3);
            }
        } else {
            uint4 z = make_uint4(0u, 0u, 0u, 0u);
#pragma unroll
            for (int q = 0; q < 8; ++q) dp[q] = z;
        }
        return;
    }
    if (bx < 446) {
        int pp = (bx - 295) * 256 + tid;
        if (pp >= NPP) return;
        uint4* dp = (uint4*)(feap + (size_t)pp * 64);
        uint4 z = make_uint4(0u, 0u, 0u, 0u);
#pragma unroll
        for (int q = 0; q < 8; ++q) dp[q] = z;
        return;
    }
    int rel = bx - 446;
    int m, i0;
    if (rel < 576)      { m = 0; i0 = rel * 256; }
    else if (rel < 720) { m = 1; i0 = (rel - 576) * 256; }
    else                { m = 2; i0 = (rel - 720) * 256; }
    const float* w = (m == 0) ? w_off : ((m == 1) ? w_dcn : w_c1);
    u16* dst = (m == 0) ? d_off : ((m == 1) ? d_dcn : d_c1);
    int NT   = (m == 0) ? 16 : 4;
    int NCO  = (m == 0) ? 216 : 64;
    int i = i0 + tid;
    if (i >= 18 * NT * 512) return;
    int j = i & 7, L = (i >> 3) & 63;
    int cot = (i >> 9) % NT, t = (i >> 9) / NT;
    int k = t * 32 + ((L >> 4) << 3) + j;
    int co = cot * 16 + (L & 15);
    float v = 0.f;
    if (co < NCO) {
        int ci, q;
        if (m == 1) { int c = k & 7, gk = k >> 3; int kk = gk % 9, g = gk / 9; ci = g*8+c; q = kk; }
        else        { q = k >> 6; ci = k & 63; }
        v = w[co * 576 + ci * 9 + q];
    }
    dst[i] = f2bf(v);
}

// ---------------------------------------------------------------------------
// GEMM off (R10, unchanged): halo A + staged B + coalesced LDS epilogue.
// ---------------------------------------------------------------------------
__global__ __launch_bounds__(256) void k_gemm_off(
    const u16* __restrict__ otp, const u16* __restrict__ wtb,
    const float* __restrict__ bias, u16* __restrict__ omr) {
    __shared__ __align__(16) char smem[32768];
    u16* lb = (u16*)smem;
    int tid = threadIdx.x;
    int wid = tid >> 6, L = tid & 63, lr = L & 15, lk = L >> 4;
    int pixblk = blockIdx.x * 64;
    int pixA = pixblk + wid * 16 + lr;
    int b = pixblk / HW;
    int hw = pixA % HW, y = hw / WW, x = hw % WW;
    int Abase = ((b * PH + y + 1) * PW + (x + 1)) * 64;

    f32x4 acc[14];
#pragma unroll
    for (int i = 0; i < 14; ++i) acc[i] = (f32x4){0.f, 0.f, 0.f, 0.f};

    for (int t = 0; t < 18; ++t) {
        if (t) __syncthreads();
        {
            const uint4* s = (const uint4*)(wtb + t * 8192);
            uint4* d = (uint4*)lb;
            for (int i = tid; i < 896; i += 256) d[i] = s[i];
        }
        __syncthreads();
        int q = t >> 1;
        int c0 = (t & 1) * 32 + lk * 8;
        int aoff = ((q / 3 - 1) * PW + (q % 3 - 1)) * 64 + c0;
        bf16x8 a = *(const bf16x8*)(otp + Abase + aoff);
        const u16* wp = lb + L * 8;
#pragma unroll
        for (int cot = 0; cot < 14; ++cot) {
            bf16x8 bf = *(const bf16x8*)(wp + cot * 512);
            acc[cot] = __builtin_amdgcn_mfma_f32_16x16x32_bf16(a, bf, acc[cot], 0, 0, 0);
        }
    }

    __syncthreads();
    u16* om_s = (u16*)smem;
#pragma unroll
    for (int cot = 0; cot < 14; ++cot) {
        int co = cot * 16 + lr;
        if (co < 216) {
            int cls = co / 72;
            int c   = co % 72;
            int g   = c / 9, kk = c % 9;
            int slot = g * 32 + cls * 9 + kk;
            float bs = bias[co];
#pragma unroll
            for (int r = 0; r < 4; ++r) {
                float v = acc[cot][r] + bs;
                if (cls == 2) v = 1.f / (1.f + __expf(-v));
                om_s[(wid * 16 + lk * 4 + r) * 256 + slot] = f2bf(v);
            }
        }
    }
    __syncthreads();
    {
        const uint4* s = (const uint4*)om_s;
        uint4* d = (uint4*)(omr + (size_t)pixblk * 256);
#pragma unroll
        for (int i = 0; i < 8; ++i) d[tid + i * 256] = s[tid + i * 256];
    }
}

// ---------------------------------------------------------------------------
// Fused deformable sampling + dcn GEMM, depth-2 tap pipeline.
// 32-pixel tile, lane=(pixel,group); fea written halo-padded (feap).
// ---------------------------------------------------------------------------
__global__ __launch_bounds__(256) void k_sdcn(
    const u16* __restrict__ xt, const u16* __restrict__ omr,
    const u16* __restrict__ wtb, const float* __restrict__ bias,
    u16* __restrict__ feap) {
    __shared__ u16 sv[32 * 576];     // 36864 B
    int tid = threadIdx.x;
    int pixblk = blockIdx.x * 32;
    int p = tid >> 3, g = tid & 7;
    int pix = pixblk + p;
    int b = pixblk / HW;
    int hw = pix % HW, h = hw / WW, w = hw % WW;

    // ---- sample: all 9 taps for (pixel p, group g), pipelined depth 2 ----
    {
        const u16* xb = xt + b * HW * 64 + g * 8;
        const uint4* op = (const uint4*)(omr + (size_t)pix * 256 + g * 32);
        uint4 o0 = op[0], o1 = op[1], o2 = op[2], o3 = op[3];
        u32 oa[16] = {o0.x,o0.y,o0.z,o0.w, o1.x,o1.y,o1.z,o1.w,
                      o2.x,o2.y,o2.z,o2.w, o3.x,o3.y,o3.z,o3.w};

        float pw00[2], pw01[2], pw10[2], pw11[2];
        int   pi00[2], pi01[2], pi10[2], pi11[2];
        uint4 q00[2], q01[2], q10[2], q11[2];

#define CALC(kk, s) {                                                          \
        float oy   = elemf(oa, (kk));                                          \
        float ox   = elemf(oa, 9 + (kk));                                      \
        float mask = elemf(oa, 18 + (kk));                                     \
        float py = (float)(h + (kk) / 3 - 1) + oy;                             \
        float px = (float)(w + (kk) % 3 - 1) + ox;                             \
        float y0f = floorf(py), x0f = floorf(px);                              \
        float fy = py - y0f, fx = px - x0f;                                    \
        int y0 = (int)y0f, x0 = (int)x0f, y1 = y0 + 1, x1 = x0 + 1;            \
        int yc0 = min(max(y0, 0), HH-1), yc1 = min(max(y1, 0), HH-1);          \
        int xc0 = min(max(x0, 0), WW-1), xc1 = min(max(x1, 0), WW-1);          \
        float u0 = 1.f - fy, u1 = fy, s0 = 1.f - fx, s1 = fx;                  \
        pw00[s] = (y0 >= 0 && y0 < HH && x0 >= 0 && x0 < WW) ? u0*s0*mask : 0.f; \
        pw01[s] = (y0 >= 0 && y0 < HH && x1 >= 0 && x1 < WW) ? u0*s1*mask : 0.f; \
        pw10[s] = (y1 >= 0 && y1 < HH && x0 >= 0 && x0 < WW) ? u1*s0*mask : 0.f; \
        pw11[s] = (y1 >= 0 && y1 < HH && x1 >= 0 && x1 < WW) ? u1*s1*mask : 0.f; \
        pi00[s] = yc0*WW + xc0; pi01[s] = yc0*WW + xc1;                        \
        pi10[s] = yc1*WW + xc0; pi11[s] = yc1*WW + xc1; }
#define ISSUE(s) {                                                             \
        q00[s] = *(const uint4*)(xb + pi00[s]*64);                             \
        q01[s] = *(const uint4*)(xb + pi01[s]*64);                             \
        q10[s] = *(const uint4*)(xb + pi10[s]*64);                             \
        q11[s] = *(const uint4*)(xb + pi11[s]*64); }

        CALC(0, 0); ISSUE(0);
#pragma unroll
        for (int kk = 0; kk < 9; ++kk) {
            int cur = kk & 1, nxt = cur ^ 1;
            if (kk < 8) { CALC(kk + 1, nxt); ISSUE(nxt); }
            float w00 = pw00[cur], w01 = pw01[cur], w10 = pw10[cur], w11 = pw11[cur];
            uint4 a4 = q00[cur], b4 = q01[cur], c4 = q10[cur], d4 = q11[cur];
            float r[8];
            {
                float a, bb, c, d;
                a=__uint_as_float(a4.x<<16); bb=__uint_as_float(b4.x<<16); c=__uint_as_float(c4.x<<16); d=__uint_as_float(d4.x<<16);
                r[0]=w00*a+w01*bb+w10*c+w11*d;
                a=__uint_as_float(a4.x&0xFFFF0000u); bb=__uint_as_float(b4.x&0xFFFF0000u); c=__uint_as_float(c4.x&0xFFFF0000u); d=__uint_as_float(d4.x&0xFFFF0000u);
                r[1]=w00*a+w01*bb+w10*c+w11*d;
                a=__uint_as_float(a4.y<<16); bb=__uint_as_float(b4.y<<16); c=__uint_as_float(c4.y<<16); d=__uint_as_float(d4.y<<16);
                r[2]=w00*a+w01*bb+w10*c+w11*d;
                a=__uint_as_float(a4.y&0xFFFF0000u); bb=__uint_as_float(b4.y&0xFFFF0000u); c=__uint_as_float(c4.y&0xFFFF0000u); d=__uint_as_float(d4.y&0xFFFF0000u);
                r[3]=w00*a+w01*bb+w10*c+w11*d;
                a=__uint_as_float(a4.z<<16); bb=__uint_as_float(b4.z<<16); c=__uint_as_float(c4.z<<16); d=__uint_as_float(d4.z<<16);
                r[4]=w00*a+w01*bb+w10*c+w11*d;
                a=__uint_as_float(a4.z&0xFFFF0000u); bb=__uint_as_float(b4.z&0xFFFF0000u); c=__uint_as_float(c4.z&0xFFFF0000u); d=__uint_as_float(d4.z&0xFFFF0000u);
                r[5]=w00*a+w01*bb+w10*c+w11*d;
                a=__uint_as_float(a4.w<<16); bb=__uint_as_float(b4.w<<16); c=__uint_as_float(c4.w<<16); d=__uint_as_float(d4.w<<16);
                r[6]=w00*a+w01*bb+w10*c+w11*d;
                a=__uint_as_float(a4.w&0xFFFF0000u); bb=__uint_as_float(b4.w&0xFFFF0000u); c=__uint_as_float(c4.w&0xFFFF0000u); d=__uint_as_float(d4.w&0xFFFF0000u);
                r[7]=w00*a+w01*bb+w10*c+w11*d;
            }
            u32 a0 = (u32)f2bf(r[0]) | ((u32)f2bf(r[1]) << 16);
            u32 a1 = (u32)f2bf(r[2]) | ((u32)f2bf(r[3]) << 16);
            u32 a2 = (u32)f2bf(r[4]) | ((u32)f2bf(r[5]) << 16);
            u32 a3 = (u32)f2bf(r[6]) | ((u32)f2bf(r[7]) << 16);
            int slot = g * 9 + kk;
            *(uint4*)((char*)sv + p * 1152 + ((slot * 16) ^ ((p & 7) << 4))) = make_uint4(a0, a1, a2, a3);
        }
#undef CALC
#undef ISSUE
    }
    __syncthreads();

    // ---- MFMA: M=32 x K=576 x N=64 ----
    int wid = tid >> 6, L = tid & 63, lr = L & 15, lk = L >> 4;
    int pbase = (wid & 1) * 16, cbase = (wid >> 1) * 2;
    int arow = pbase + lr;

    f32x4 acc[2];
    acc[0] = (f32x4){0.f, 0.f, 0.f, 0.f};
    acc[1] = (f32x4){0.f, 0.f, 0.f, 0.f};
#pragma unroll
    for (int t = 0; t < 18; ++t) {
        bf16x8 a = *(const bf16x8*)((const char*)sv + arow * 1152 + (((t * 4 + lk) * 16) ^ ((arow & 7) << 4)));
#pragma unroll
        for (int ct = 0; ct < 2; ++ct) {
            bf16x8 bf = *(const bf16x8*)(wtb + ((t * 4 + cbase + ct) * 64 + L) * 8);
            acc[ct] = __builtin_amdgcn_mfma_f32_16x16x32_bf16(a, bf, acc[ct], 0, 0, 0);
        }
    }
    // halo-padded fea write: all 32 pixels share row hb; col = wb + pixel-offset
    int hwb = pixblk % HW;
    int hb = hwb / WW, wb = hwb % WW;
#pragma unroll
    for (int ct = 0; ct < 2; ++ct) {
        int co = (cbase + ct) * 16 + lr;
        float bs = bias[co];
#pragma unroll
        for (int r = 0; r < 4; ++r) {
            float v = acc[ct][r] + bs;
            v = (v >= 0.f) ? v : 0.2f * v;
            feap[((b * PH + hb + 1) * PW + (wb + 1 + pbase + lk * 4 + r)) * 64 + co] = f2bf(v);
        }
    }
}

// ---------------------------------------------------------------------------
// GEMM conv1: out (f32 NCHW) = im2col(feap) x w_conv1 + bias + x  (branchless A)
// ---------------------------------------------------------------------------
__global__ __launch_bounds__(256) void k_gemm_c1(
    const u16* __restrict__ feap, const u16* __restrict__ wtb,
    const float* __restrict__ bias, const float* __restrict__ xres,
    float* __restrict__ out) {
    __shared__ __align__(16) char smraw[36864];
    u16* lb = (u16*)smraw;
    int tid = threadIdx.x;
    int wid = tid >> 6, L = tid & 63, lr = L & 15, lk = L >> 4;
    int pixblk = blockIdx.x * 64;
    int pixA = pixblk + wid * 16 + lr;
    int b = pixblk / HW;
    int hw = pixA % HW, y = hw / WW, x = hw % WW;
    int Abase = ((b * PH + y + 1) * PW + (x + 1)) * 64;

    f32x4 acc[4];
#pragma unroll
    for (int i = 0; i < 4; ++i) acc[i] = (f32x4){0.f, 0.f, 0.f, 0.f};

    {
        const uint4* s = (const uint4*)wtb;
        uint4* d = (uint4*)lb;
#pragma unroll
        for (int i = 0; i < 9; ++i) d[tid + i * 256] = s[tid + i * 256];
    }
    __syncthreads();
    for (int half = 0; half < 2; ++half) {
        int tbase = half * 9;
#pragma unroll
        for (int tl = 0; tl < 9; ++tl) {
            int t = tbase + tl;
            int q = t >> 1;
            int c0 = (t & 1) * 32 + lk * 8;
            int aoff = ((q / 3 - 1) * PW + (q % 3 - 1)) * 64 + c0;
            bf16x8 a = *(const bf16x8*)(feap + Abase + aoff);
            const u16* wp = lb + (tl * 256 + L) * 8;
#pragma unroll
            for (int cot = 0; cot < 4; ++cot) {
                bf16x8 bf = *(const bf16x8*)(wp + cot * 512);
                acc[cot] = __builtin_amdgcn_mfma_f32_16x16x32_bf16(a, bf, acc[cot], 0, 0, 0);
            }
        }
        __syncthreads();
        if (half == 0) {
            const uint4* s = (const uint4*)(wtb + 18432);
            uint4* d = (uint4*)lb;
#pragma unroll
            for (int i = 0; i < 9; ++i) d[tid + i * 256] = s[tid + i * 256];
            __syncthreads();
        }
    }
    float* ob = (float*)smraw;
#pragma unroll
    for (int cot = 0; cot < 4; ++cot) {
#pragma unroll
        for (int r = 0; r < 4; ++r)
            ob[(wid * 16 + lk * 4 + r) * 66 + cot * 16 + lr] = acc[cot][r];
    }
    __syncthreads();
    int p = tid & 63, cg = tid >> 6;
    int hw0 = pixblk % HW;
#pragma unroll
    for (int i = 0; i < 16; ++i) {
        int co = cg * 16 + i;
        int idx = (b * 64 + co) * HW + hw0 + p;
        out[idx] = ob[p * 66 + co] + bias[co] + xres[idx];
    }
}

// ---------------------------------------------------------------------------
extern "C" void kernel_launch(void* const* d_in, const int* in_sizes, int n_in,
                              void* d_out, int out_size, void* d_ws, size_t ws_size,
                              hipStream_t stream) {
    const float* x       = (const float*)d_in[0];
    const float* offset  = (const float*)d_in[1];
    const float* w_off   = (const float*)d_in[2];
    const float* b_off   = (const float*)d_in[3];
    const float* w_dcn   = (const float*)d_in[4];
    const float* b_dcn   = (const float*)d_in[5];
    const float* w_conv1 = (const float*)d_in[6];
    const float* b_conv1 = (const float*)d_in[7];
    float* out = (float*)d_out;

    char* ws = (char*)d_ws;
    u16* omr     = (u16*)(ws);                        // 36864*256*2 = 18,874,368
    u16* xt      = (u16*)(ws + 18874368);             //  4,718,592
    u16* otp     = (u16*)(ws + 23592960);             // 38416*64*2 = 4,917,248 (halo)
    u16* feap    = (u16*)(ws + 28510208);             // 38416*64*2 = 4,917,248 (halo)
    u16* wtb_off = (u16*)(ws + 33427456);             // 18*16*512*2 = 294,912
    u16* wtb_dcn = (u16*)(ws + 33722368);             //     73,728
    u16* wtb_c1  = (u16*)(ws + 33796096);             //     73,728

    hipLaunchKernelGGL(k_prep, dim3(1310), dim3(256), 0, stream,
                       x, offset, w_off, w_dcn, w_conv1, xt, otp, feap,
                       wtb_off, wtb_dcn, wtb_c1);
    hipLaunchKernelGGL(k_gemm_off, dim3(576), dim3(256), 0, stream, otp, wtb_off, b_off, omr);
    hipLaunchKernelGGL(k_sdcn, dim3(1152), dim3(256), 0, stream, xt, omr, wtb_dcn, b_dcn, feap);
    hipLaunchKernelGGL(k_gemm_c1, dim3(576), dim3(256), 0, stream, feap, wtb_c1, b_conv1, x, out);
}